// Round 17
// baseline (218.832 us; speedup 1.0000x reference)
//
#include <hip/hip_runtime.h>

// LIF recurrence, T=4, TAU=1.0, THRESH=1.0.
// mem = mem + x[t]; spike = (mem - 1 > 0); mem = spike ? 0 : mem.
//
// v11: v7's guaranteed 8-deep bursts + NT cache policy = the untested
// combination. History: v7 (global_load_lds, aux=0) was NULL — but measured
// in the FRAGMENTED-stream regime, where v9 later proved L3 half-hits were
// the binding limiter (NT loads: 77->67us). A null under a different binding
// bottleneck is masked, not refuted. v11 re-tests guaranteed burst depth in
// the clean-stream regime: aux=2 sets the NT CPol bit (gfx940-family:
// SC0=1, NT=2) on global_load_lds -> full-miss contiguous reads, fire-and-
// forget, zero VGPR cost, consumed behind counted vmcnt(6) so NT stores
// (younger in queue) never block the wait.
// Single variable vs v7: load cache policy. vs v9/v10: burst depth.
// Signals: 50-60us => depth was masked, done. ~217 bench => all software
// axes exhausted (depth x cleanliness matrix complete) -> declare ceiling.

#define LIF_T 4
#define CHUNK_F4 512   // float4 per plane per block (8KB/plane, 32KB LDS total)

typedef float f32x4 __attribute__((ext_vector_type(4)));

#define AS1 __attribute__((address_space(1)))
#define AS3 __attribute__((address_space(3)))

__device__ __forceinline__ f32x4 lif_step(f32x4& mem, f32x4 xt) {
    mem.x += xt.x;
    mem.y += xt.y;
    mem.z += xt.z;
    mem.w += xt.w;
    f32x4 sp;
    sp.x = (mem.x > 1.0f) ? 1.0f : 0.0f;
    sp.y = (mem.y > 1.0f) ? 1.0f : 0.0f;
    sp.z = (mem.z > 1.0f) ? 1.0f : 0.0f;
    sp.w = (mem.w > 1.0f) ? 1.0f : 0.0f;
    mem.x = (sp.x > 0.f) ? 0.f : mem.x;
    mem.y = (sp.y > 0.f) ? 0.f : mem.y;
    mem.z = (sp.z > 0.f) ? 0.f : mem.z;
    mem.w = (sp.w > 0.f) ? 0.f : mem.w;
    return sp;
}

__global__ __launch_bounds__(256) void
lif_spike_kernel(const float* __restrict__ x, float* __restrict__ out, int n_vec) {
    __shared__ f32x4 lds[LIF_T][CHUNK_F4];

    const int tid  = threadIdx.x;
    const int wave = tid >> 6;       // 0..3
    const int lane = tid & 63;
    const int b0   = blockIdx.x * CHUNK_F4;   // block's first float4 per plane

    const f32x4* __restrict__ xv = reinterpret_cast<const f32x4*>(x);
    f32x4* __restrict__ ov = reinterpret_cast<f32x4*>(out);

    if (b0 + CHUNK_F4 <= n_vec) {
        // ---- fast path (exact cover: 4096 blocks x 512 == n_vec) ----
        // Burst phase: 8 fire-and-forget 1KB NT loads per wave, zero VGPR
        // cost, wave-private LDS slices (no barrier needed).
#pragma unroll
        for (int t = 0; t < LIF_T; ++t) {
#pragma unroll
            for (int s = 0; s < 2; ++s) {
                const int l4 = wave * 128 + s * 64;
                const f32x4* g = xv + (size_t)t * n_vec + b0 + l4 + lane;
                __builtin_amdgcn_global_load_lds(
                    (const AS1 void*)g, (AS3 void*)&lds[t][l4], 16, 0, /*aux=NT*/2);
            }
        }

        f32x4 mem[2];
        mem[0] = (f32x4){0.f, 0.f, 0.f, 0.f};
        mem[1] = (f32x4){0.f, 0.f, 0.f, 0.f};

        // Consume plane-by-plane. vmcnt queue at plane t:
        // [L(2t), L(2t+1), ..., L7, S...] -> vmcnt(6) retires exactly the two
        // oldest (this plane's loads); stores are youngest and never block.
#pragma unroll
        for (int t = 0; t < LIF_T; ++t) {
            asm volatile("s_waitcnt vmcnt(6)" ::: "memory");
            __builtin_amdgcn_sched_barrier(0);
#pragma unroll
            for (int c = 0; c < 2; ++c) {
                const int l4 = wave * 128 + c * 64 + lane;
                f32x4 xt = lds[t][l4];
                f32x4 sp = lif_step(mem[c], xt);
                __builtin_nontemporal_store(sp, &ov[(size_t)t * n_vec + b0 + l4]);
            }
        }
    } else {
        // ---- tail path (not taken in the exact bench shape) ----
        f32x4 memc[2];
        memc[0] = (f32x4){0.f, 0.f, 0.f, 0.f};
        memc[1] = (f32x4){0.f, 0.f, 0.f, 0.f};
#pragma unroll
        for (int t = 0; t < LIF_T; ++t) {
#pragma unroll
            for (int c = 0; c < 2; ++c) {
                const int idx = b0 + wave * 128 + c * 64 + lane;
                if (idx < n_vec) {
                    f32x4 xt = __builtin_nontemporal_load(&xv[(size_t)t * n_vec + idx]);
                    f32x4 sp = lif_step(memc[c], xt);
                    __builtin_nontemporal_store(sp, &ov[(size_t)t * n_vec + idx]);
                }
            }
        }
    }
}

extern "C" void kernel_launch(void* const* d_in, const int* in_sizes, int n_in,
                              void* d_out, int out_size, void* d_ws, size_t ws_size,
                              hipStream_t stream) {
    const float* x = (const float*)d_in[0];
    float* out = (float*)d_out;

    int n = out_size / LIF_T;      // elements per timestep (8,388,608)
    int n_vec = n / 4;             // float4 groups per timestep (2,097,152)

    const int block = 256;
    int grid = (n_vec + CHUNK_F4 - 1) / CHUNK_F4;   // 4096
    lif_spike_kernel<<<grid, block, 0, stream>>>(x, out, n_vec);
}